// Round 3
// baseline (201.645 us; speedup 1.0000x reference)
//
#include <hip/hip_runtime.h>
#include <hip/hip_bf16.h>

typedef __attribute__((ext_vector_type(8))) short short8;
typedef __attribute__((ext_vector_type(4))) float f32x4;

static constexpr int MT = 32768;  // rows
static constexpr int KT = 256;    // contraction
static constexpr int CT = 4096;   // classes

// round-to-nearest-even float -> bf16 bits
__device__ __forceinline__ unsigned short f2b(float f) {
  unsigned int b = __float_as_uint(f);
  b += 0x7FFFu + ((b >> 16) & 1u);
  return (unsigned short)(b >> 16);
}

__global__ void __launch_bounds__(256) cvtA_kernel(const float* __restrict__ A,
                                                   unsigned short* __restrict__ Abf) {
  int i = blockIdx.x * 256 + threadIdx.x;  // 8 floats per lane
  const float4 v0 = reinterpret_cast<const float4*>(A)[2 * i];
  const float4 v1 = reinterpret_cast<const float4*>(A)[2 * i + 1];
  short8 o;
  o[0] = (short)f2b(v0.x); o[1] = (short)f2b(v0.y);
  o[2] = (short)f2b(v0.z); o[3] = (short)f2b(v0.w);
  o[4] = (short)f2b(v1.x); o[5] = (short)f2b(v1.y);
  o[6] = (short)f2b(v1.z); o[7] = (short)f2b(v1.w);
  reinterpret_cast<short8*>(Abf)[i] = o;
}

// B [KT][CT] fp32 -> Bt [CT][KT] bf16 (LDS-tiled transpose)
__global__ void __launch_bounds__(1024) cvtB_kernel(const float* __restrict__ B,
                                                    unsigned short* __restrict__ Bt) {
  __shared__ unsigned short tile[32][33];
  int tx = threadIdx.x & 31, ty = threadIdx.x >> 5;
  int c0 = blockIdx.x * 32, k0 = blockIdx.y * 32;
  tile[ty][tx] = f2b(B[(size_t)(k0 + ty) * CT + c0 + tx]);
  __syncthreads();
  Bt[(size_t)(c0 + ty) * KT + k0 + tx] = tile[tx][ty];
}

__device__ __forceinline__ void gload16(const void* g, void* l) {
  __builtin_amdgcn_global_load_lds(
      (const __attribute__((address_space(1))) void*)g,
      (__attribute__((address_space(3))) void*)l, 16, 0, 0);
}

__global__ void __launch_bounds__(256, 2) gemm_kernel(const unsigned short* __restrict__ Abf,
                                                      const unsigned short* __restrict__ Btw,
                                                      float* __restrict__ O) {
  constexpr int BM = 128, BN = 128, BK = 64;
  // [buf][A=0/B=1][128 rows][64 k] bf16, XOR-swizzled in 16B chunks: 2 x 32 KB
  __shared__ __align__(16) unsigned short lds[2][2][BM * BK];

  int bid = blockIdx.x;
  // XCD-aware swizzle; 8192 % 8 == 0 so the simple form is bijective
  int wg = (bid & 7) * (8192 / 8) + (bid >> 3);
  int tc = wg & 31;   // 32 col tiles
  int tr = wg >> 5;   // 256 row tiles
  int r0 = tr * BM, c0 = tc * BN;

  int tid = threadIdx.x;
  int lane = tid & 63, wid = tid >> 6;
  int wr = wid >> 1, wc = wid & 1;      // 2x2 waves, each owns 64x64
  int l15 = lane & 15, l4 = lane >> 4;
  int l8lo = lane & 7, l8hi = lane >> 3;  // chunk-in-row, row-in-8 for staging

  f32x4 acc[4][4] = {};  // acc[n][m] (swapped-operand orientation)

  // Stage one 128x64 bf16 tile into lds[buf][ab]: 4 x gload16 per thread.
  // LDS dest is linear (wave-uniform base + lane*16); source column chunk is
  // pre-XOR-swizzled so a swizzled ds_read sees the right data (rule #21).
  auto stage = [&](int buf, int ab, const unsigned short* __restrict__ src,
                   int rowbase, int t) {
#pragma unroll
    for (int i = 0; i < 4; ++i) {
      int row = (wid * 4 + i) * 8 + l8hi;          // block-local row 0..127
      int schunk = l8lo ^ l8hi;                    // (chunk) ^ (row & 7)
      gload16(src + (size_t)(rowbase + row) * KT + t * BK + schunk * 8,
              &lds[buf][ab][(wid * 4 + i) * 512]); // wave-uniform 1KB slot
    }
  };

  // Compute one K-tile (BK=64): 16 ds_read_b128 + 32 MFMA per wave.
  auto compute = [&](int buf) {
    short8 af[4][2], bf[4][2];
#pragma unroll
    for (int m = 0; m < 4; ++m)
#pragma unroll
      for (int ks = 0; ks < 2; ++ks) {
        int rowA = wr * 64 + m * 16 + l15;
        int ca = (ks * 4 + l4) ^ (l15 & 7);        // de-swizzle chunk
        af[m][ks] = *reinterpret_cast<const short8*>(&lds[buf][0][rowA * BK + ca * 8]);
        int rowB = wc * 64 + m * 16 + l15;
        bf[m][ks] = *reinterpret_cast<const short8*>(&lds[buf][1][rowB * BK + ca * 8]);
      }
#pragma unroll
    for (int n = 0; n < 4; ++n)
#pragma unroll
      for (int m = 0; m < 4; ++m)
#pragma unroll
        for (int ks = 0; ks < 2; ++ks)
          // swapped operands: D[class][mrow] -> lane holds 4 consecutive C columns
          acc[n][m] = __builtin_amdgcn_mfma_f32_16x16x32_bf16(bf[n][ks], af[m][ks],
                                                              acc[n][m], 0, 0, 0);
  };

  // K_TILES = 4, fully unrolled, counted vmcnt (never drain mid-loop).
  stage(0, 0, Abf, r0, 0); stage(0, 1, Btw, c0, 0);   // 8 instrs
  stage(1, 0, Abf, r0, 1); stage(1, 1, Btw, c0, 1);   // 16 in flight
  asm volatile("s_waitcnt vmcnt(8)" ::: "memory");     // tile0 landed (own)
  __builtin_amdgcn_s_barrier();                        // tile0 landed (all)
  asm volatile("" ::: "memory");
  compute(0);
  __builtin_amdgcn_s_barrier();                        // buf0 free
  asm volatile("" ::: "memory");
  stage(0, 0, Abf, r0, 2); stage(0, 1, Btw, c0, 2);   // tile2 -> buf0
  asm volatile("s_waitcnt vmcnt(8)" ::: "memory");     // tile1 landed (own)
  __builtin_amdgcn_s_barrier();
  asm volatile("" ::: "memory");
  compute(1);
  __builtin_amdgcn_s_barrier();                        // buf1 free
  asm volatile("" ::: "memory");
  stage(1, 0, Abf, r0, 3); stage(1, 1, Btw, c0, 3);   // tile3 -> buf1
  asm volatile("s_waitcnt vmcnt(8)" ::: "memory");     // tile2 landed (own)
  __builtin_amdgcn_s_barrier();
  asm volatile("" ::: "memory");
  compute(0);
  asm volatile("s_waitcnt vmcnt(0)" ::: "memory");     // tile3 landed (own)
  __builtin_amdgcn_s_barrier();
  asm volatile("" ::: "memory");
  compute(1);

  // Epilogue: swapped layout gives each lane 4 consecutive columns -> dwordx4.
  const float s = 1.0f / 16.0f;
#pragma unroll
  for (int n = 0; n < 4; ++n)
#pragma unroll
    for (int m = 0; m < 4; ++m) {
      f32x4 v = acc[n][m];
      v[0] *= s; v[1] *= s; v[2] *= s; v[3] *= s;
      size_t off = (size_t)(r0 + wr * 64 + m * 16 + l15) * CT +
                   (c0 + wc * 64 + n * 16 + l4 * 4);
      *reinterpret_cast<f32x4*>(O + off) = v;
    }
}

// Correct-but-slow insurance path if ws_size is too small for the bf16 copies.
__global__ void __launch_bounds__(256) naive_kernel(const float* __restrict__ A,
                                                    const float* __restrict__ B,
                                                    float* __restrict__ O) {
  size_t i = (size_t)blockIdx.x * 256 + threadIdx.x;
  int col = (int)(i & (size_t)(CT - 1));
  int row = (int)(i >> 12);
  float s = 0.f;
  for (int k = 0; k < KT; ++k)
    s += A[(size_t)row * KT + k] * B[(size_t)k * CT + col];
  O[i] = s * (1.0f / 16.0f);
}

extern "C" void kernel_launch(void* const* d_in, const int* in_sizes, int n_in,
                              void* d_out, int out_size, void* d_ws, size_t ws_size,
                              hipStream_t stream) {
  const float* A = (const float*)d_in[0];
  const float* B = (const float*)d_in[1];
  float* O = (float*)d_out;
  const size_t needA = (size_t)MT * KT * sizeof(unsigned short);  // 16 MiB
  const size_t needB = (size_t)CT * KT * sizeof(unsigned short);  //  2 MiB
  if (ws_size >= needA + needB) {
    unsigned short* Abf = (unsigned short*)d_ws;
    unsigned short* Btw = (unsigned short*)((char*)d_ws + needA);
    cvtA_kernel<<<MT * KT / 8 / 256, 256, 0, stream>>>(A, Abf);
    cvtB_kernel<<<dim3(CT / 32, KT / 32), 1024, 0, stream>>>(B, Btw);
    gemm_kernel<<<(MT / 128) * (CT / 128), 256, 0, stream>>>(Abf, Btw, O);
  } else {
    naive_kernel<<<(unsigned)((size_t)MT * CT / 256), 256, 0, stream>>>(A, B, O);
  }
}